// Round 11
// baseline (213.750 us; speedup 1.0000x reference)
//
#include <hip/hip_runtime.h>
#include <hip/hip_bf16.h>
#include <math.h>

typedef __attribute__((ext_vector_type(8)))  short short8;
typedef __attribute__((ext_vector_type(4)))  float floatx4;
typedef __attribute__((ext_vector_type(16))) float f32x16;

#define L_SEQ 2048
#define NHEADS 8
#define EDIM 64
#define PLANE (L_SEQ * EDIM) // shorts per (b,h) plane in workspace (131072)
#define LOG2E 1.4426950408889634f

union U8 { unsigned u[4]; short8 s; };

__device__ __forceinline__ unsigned cvt_pk(float lo, float hi) {
    unsigned r;
    asm("v_cvt_pk_bf16_f32 %0, %1, %2" : "=v"(r) : "v"(lo), "v"(hi));
    return r;
}
__device__ __forceinline__ short8 pack8(floatx4 a, floatx4 b) {
    U8 r;
    r.u[0] = cvt_pk(a[0], a[1]); r.u[1] = cvt_pk(a[2], a[3]);
    r.u[2] = cvt_pk(b[0], b[1]); r.u[3] = cvt_pk(b[2], b[3]);
    return r.s;
}
__device__ __forceinline__ unsigned xswap32(unsigned v) {
    return (unsigned)__shfl_xor((int)v, 32);
}

// ---------- prep: K,V fp32 -> bf16 in MFMA-fragment-linear order ----------
__global__ __launch_bounds__(256) void prep_frag(
    const float* __restrict__ K, const float* __restrict__ V,
    unsigned short* __restrict__ Kf, unsigned short* __restrict__ Vf)
{
    __shared__ unsigned short Tk[64][72];   // [row][e]
    __shared__ unsigned short Tv[64][72];   // [e][k]
    const int st  = blockIdx.x;        // 64-seq-row tile (32 tiles)
    const int bh  = blockIdx.y;        // b*8+h
    const int b   = bh >> 3, h = bh & 7;
    const int tid = threadIdx.x;
    const int sb  = st * 64;

    {   // load K rows coalesced -> Tk
        int s0 = tid >> 3, e0 = (tid & 7) * 8;
        #pragma unroll
        for (int j = 0; j < 2; ++j) {
            int s = s0 + j * 32;
            const float* kp = K + ((size_t)(b * L_SEQ + sb + s) * NHEADS + h) * EDIM + e0;
            floatx4 f0 = *(const floatx4*)kp;
            floatx4 f1 = *(const floatx4*)(kp + 4);
            *(short8*)&Tk[s][e0] = pack8(f0, f1);
        }
    }
    {   // load V rows coalesced (lane = e) -> Tv transposed
        int e = tid & 63, sg = tid >> 6;
        #pragma unroll
        for (int j = 0; j < 16; ++j) {
            int s = sg * 16 + j;
            float v = V[((size_t)(b * L_SEQ + sb + s) * NHEADS + h) * EDIM + e];
            union { float f; unsigned u; } cv; cv.f = v;
            Tv[e][s] = (unsigned short)((cv.u + 0x7FFFu + ((cv.u >> 16) & 1u)) >> 16);
        }
    }
    __syncthreads();
    {   // write Kf fragment-linear (coalesced)
        int s2 = tid >> 7, t7 = tid & 127, ec = t7 >> 5, l31 = t7 & 31;
        #pragma unroll
        for (int hi = 0; hi < 2; ++hi) {
            int row = s2 * 32 + l31, e = ec * 16 + hi * 8;
            short8 v = *(const short8*)&Tk[row][e];
            size_t unit = (((size_t)bh * 64 + st * 2 + s2) * 4 + ec) * 64 + hi * 32 + l31;
            *(short8*)&Kf[unit * 8] = v;
        }
    }
    {   // write Vf fragment-linear (coalesced)
        int s2 = tid >> 7, t7 = tid & 127, et = t7 >> 6, lane = t7 & 63;
        #pragma unroll
        for (int c = 0; c < 2; ++c) {
            int e = et * 32 + (lane & 31), k0 = s2 * 32 + c * 16 + (lane >> 5) * 8;
            short8 v = *(const short8*)&Tv[e][k0];
            size_t unit = ((((size_t)bh * 64 + st * 2 + s2) * 2 + et) * 2 + c) * 64 + lane;
            *(short8*)&Vf[unit * 8] = v;
        }
    }
}

// load a subtile's 8 fragments into named regs
#define LOAD8(K0,K1,K2,K3,V0,V1,V2,V3,S) do {                         \
    const unsigned short* _kp = kfb + (size_t)(S) * 2048;             \
    const unsigned short* _vp = vfb + (size_t)(S) * 2048;             \
    K0 = *(const short8*)(_kp);        K1 = *(const short8*)(_kp + 512);  \
    K2 = *(const short8*)(_kp + 1024); K3 = *(const short8*)(_kp + 1536); \
    V0 = *(const short8*)(_vp);        V1 = *(const short8*)(_vp + 512);  \
    V2 = *(const short8*)(_vp + 1024); V3 = *(const short8*)(_vp + 1536); \
} while (0)

// full per-subtile compute on named fragment regs
#define BODY(K0,K1,K2,K3,V0,V1,V2,V3,S32) do {                        \
    const bool diag = ((S32) == qg);                                  \
    const int  kv0s = (S32) * 32;                                     \
    f32x16 st = {};                                                   \
    __builtin_amdgcn_s_setprio(1);                                    \
    st = __builtin_amdgcn_mfma_f32_32x32x16_bf16(K0, qfrag[0], st, 0, 0, 0); \
    st = __builtin_amdgcn_mfma_f32_32x32x16_bf16(K1, qfrag[1], st, 0, 0, 0); \
    st = __builtin_amdgcn_mfma_f32_32x32x16_bf16(K2, qfrag[2], st, 0, 0, 0); \
    st = __builtin_amdgcn_mfma_f32_32x32x16_bf16(K3, qfrag[3], st, 0, 0, 0); \
    __builtin_amdgcn_s_setprio(0);                                    \
    float p[16];                                                      \
    if (!diag) {                                                      \
        const float* bptr = &bias_lds[qrow - kv0s - hi4];             \
        _Pragma("unroll")                                             \
        for (int r = 0; r < 16; ++r)                                  \
            p[r] = exp2f(fmaf(qscale, st[r], bptr[-(r & 3) - 8 * (r >> 2)])); \
    } else {                                                          \
        _Pragma("unroll")                                             \
        for (int r = 0; r < 16; ++r) {                                \
            int kidx = (r & 3) + 8 * (r >> 2) + hi4;                  \
            int d = q32 - kidx;                                       \
            int dc = d < 0 ? 0 : d;                                   \
            float ex = exp2f(fmaf(qscale, st[r], bias_lds[dc]));      \
            p[r] = (d >= 0) ? ex : 0.0f;                              \
        }                                                             \
    }                                                                 \
    float s8[8], s4[4], s2[2];                                        \
    _Pragma("unroll")                                                 \
    for (int i = 0; i < 8; ++i) s8[i] = p[2*i] + p[2*i+1];            \
    _Pragma("unroll")                                                 \
    for (int i = 0; i < 4; ++i) s4[i] = s8[2*i] + s8[2*i+1];          \
    s2[0] = s4[0] + s4[1]; s2[1] = s4[2] + s4[3];                     \
    float tsum = s2[0] + s2[1];                                       \
    l_run += tsum + __shfl_xor(tsum, 32);                             \
    unsigned a0 = cvt_pk(p[0],  p[1]),  b0 = cvt_pk(p[2],  p[3]);     \
    unsigned c0 = cvt_pk(p[4],  p[5]),  d0 = cvt_pk(p[6],  p[7]);     \
    unsigned a1 = cvt_pk(p[8],  p[9]),  b1 = cvt_pk(p[10], p[11]);    \
    unsigned c1 = cvt_pk(p[12], p[13]), d1 = cvt_pk(p[14], p[15]);    \
    unsigned as0 = xswap32(a0), bs0 = xswap32(b0);                    \
    unsigned cs0 = xswap32(c0), ds0 = xswap32(d0);                    \
    unsigned as1 = xswap32(a1), bs1 = xswap32(b1);                    \
    unsigned cs1 = xswap32(c1), ds1 = xswap32(d1);                    \
    U8 pf0;                                                           \
    pf0.u[0] = hi ? cs0 : a0;                                         \
    pf0.u[1] = hi ? ds0 : b0;                                         \
    pf0.u[2] = hi ? c0  : as0;                                        \
    pf0.u[3] = hi ? d0  : bs0;                                        \
    U8 pf1;                                                           \
    pf1.u[0] = hi ? cs1 : a1;                                         \
    pf1.u[1] = hi ? ds1 : b1;                                         \
    pf1.u[2] = hi ? c1  : as1;                                        \
    pf1.u[3] = hi ? d1  : bs1;                                        \
    __builtin_amdgcn_s_setprio(1);                                    \
    o_acc[0] = __builtin_amdgcn_mfma_f32_32x32x16_bf16(pf0.s, V0, o_acc[0], 0, 0, 0); \
    o_acc[0] = __builtin_amdgcn_mfma_f32_32x32x16_bf16(pf1.s, V1, o_acc[0], 0, 0, 0); \
    o_acc[1] = __builtin_amdgcn_mfma_f32_32x32x16_bf16(pf0.s, V2, o_acc[1], 0, 0, 0); \
    o_acc[1] = __builtin_amdgcn_mfma_f32_32x32x16_bf16(pf1.s, V3, o_acc[1], 0, 0, 0); \
    __builtin_amdgcn_s_setprio(0);                                    \
} while (0)

// ---------- attention: 32 q-rows/block, 4 kv-quarter waves, 2-deep pipeline ----------
__global__ __launch_bounds__(256, 4) void attn_fwd(
    const float* __restrict__ Q, const unsigned short* __restrict__ Kf,
    const unsigned short* __restrict__ Vf, const float* __restrict__ table,
    float* __restrict__ Out)
{
    __shared__ __align__(16) float bias_lds[L_SEQ];   // 8 KB (log2e-scaled)
    __shared__ __align__(16) float osc[2][32][64];    // 16 KB merge scratch, lane-major
    __shared__ float lsc[2][64];

    const int qg   = 63 - blockIdx.x;          // heavy q-groups dispatch first
    const int bh   = blockIdx.y;
    const int b    = bh >> 3, h = bh & 7;
    const int tid  = threadIdx.x;
    const int w    = tid >> 6, lane = tid & 63;
    const int q32  = lane & 31;
    const int hi   = lane >> 5;
    const int hi4  = 4 * hi, hi8 = 8 * hi;
    const int qs   = qg * 32;
    const int qrow = qs + q32;
    const int nsub = qg + 1;                   // 32-row kv subtiles

    const int dmax = nsub * 32;
    for (int d = tid; d < dmax; d += 256) {
        int bucket;
        if (d < 16) bucket = d;
        else {
            float t = logf((float)d * 0.0625f) / 2.0794415416798357f * 16.0f;
            int bb = 16 + (int)t;
            bucket = bb < 31 ? bb : 31;
        }
        bias_lds[d] = table[bucket * NHEADS + h] * LOG2E;
    }

    const float* qptr = Q + ((size_t)(b * L_SEQ + qrow) * NHEADS + h) * EDIM;
    short8 qfrag[4];
    #pragma unroll
    for (int ec = 0; ec < 4; ++ec) {
        floatx4 f0 = *(const floatx4*)(qptr + ec * 16 + hi8);
        floatx4 f1 = *(const floatx4*)(qptr + ec * 16 + hi8 + 4);
        qfrag[ec] = pack8(f0, f1);
    }
    __syncthreads();    // bias ready

    const int len = (nsub + 3) >> 2;
    const int r0  = w * len;
    const int r1  = (r0 + len < nsub) ? r0 + len : nsub;
    const int cnt = r1 - r0;

    const unsigned short* kfb = Kf + (size_t)bh * PLANE + lane * 8;
    const unsigned short* vfb = Vf + (size_t)bh * PLANE + lane * 8;

    float  l_run = 0.f;
    f32x16 o_acc[2] = {};

    const float qscale = 0.125f * LOG2E;

    if (cnt > 0) {
        short8 kA0, kA1, kA2, kA3, vA0, vA1, vA2, vA3;
        short8 kB0, kB1, kB2, kB3, vB0, vB1, vB2, vB3;
        LOAD8(kA0, kA1, kA2, kA3, vA0, vA1, vA2, vA3, r0);
        int i = 0;
        while (i + 2 <= cnt) {
            LOAD8(kB0, kB1, kB2, kB3, vB0, vB1, vB2, vB3, r0 + i + 1);
            BODY(kA0, kA1, kA2, kA3, vA0, vA1, vA2, vA3, r0 + i);
            if (i + 2 < cnt)
                LOAD8(kA0, kA1, kA2, kA3, vA0, vA1, vA2, vA3, r0 + i + 2);
            BODY(kB0, kB1, kB2, kB3, vB0, vB1, vB2, vB3, r0 + i + 1);
            i += 2;
        }
        if (i < cnt)
            BODY(kA0, kA1, kA2, kA3, vA0, vA1, vA2, vA3, r0 + i);
    }

    // ---- additive merge of the 4 kv-quarters (2-round LDS tree, lane-major) ----
    __syncthreads();
    if (w & 1) {
        int slot = w >> 1;
        #pragma unroll
        for (int et = 0; et < 2; ++et)
            #pragma unroll
            for (int r = 0; r < 16; ++r)
                osc[slot][et * 16 + r][lane] = o_acc[et][r];
        lsc[slot][lane] = l_run;
    }
    __syncthreads();
    if (!(w & 1)) {
        int slot = w >> 1;
        l_run += lsc[slot][lane];
        #pragma unroll
        for (int et = 0; et < 2; ++et)
            #pragma unroll
            for (int r = 0; r < 16; ++r)
                o_acc[et][r] += osc[slot][et * 16 + r][lane];
    }
    __syncthreads();
    if (w == 2) {
        #pragma unroll
        for (int et = 0; et < 2; ++et)
            #pragma unroll
            for (int r = 0; r < 16; ++r)
                osc[0][et * 16 + r][lane] = o_acc[et][r];
        lsc[0][lane] = l_run;
    }
    __syncthreads();
    if (w == 0) {
        l_run += lsc[0][lane];
        #pragma unroll
        for (int et = 0; et < 2; ++et)
            #pragma unroll
            for (int r = 0; r < 16; ++r)
                o_acc[et][r] += osc[0][et * 16 + r][lane];

        float inv = 1.0f / l_run;
        #pragma unroll
        for (int r = 0; r < 16; ++r) {
            int qv = (r & 3) + 8 * (r >> 2) + hi4;
            float iv = __shfl(inv, qv);
            float* op = Out + ((size_t)(b * L_SEQ + qs + qv) * NHEADS + h) * EDIM + q32;
            op[0]  = o_acc[0][r] * iv;
            op[32] = o_acc[1][r] * iv;
        }
    }
}

extern "C" void kernel_launch(void* const* d_in, const int* in_sizes, int n_in,
                              void* d_out, int out_size, void* d_ws, size_t ws_size,
                              hipStream_t stream) {
    const float* Q     = (const float*)d_in[0];
    const float* K     = (const float*)d_in[1];
    const float* V     = (const float*)d_in[2];
    const float* table = (const float*)d_in[3];
    float* Out = (float*)d_out;
    unsigned short* Kf = (unsigned short*)d_ws;                 // 8.4 MB
    unsigned short* Vf = Kf + (size_t)4 * NHEADS * PLANE;       // 8.4 MB
    (void)in_sizes; (void)n_in; (void)out_size; (void)ws_size;

    dim3 pgrid(32, 32);
    prep_frag<<<pgrid, 256, 0, stream>>>(K, V, Kf, Vf);
    dim3 grid(64, 32);   // 64 q-groups (32 rows, 4 kv-quarters) x (B*H = 32)
    attn_fwd<<<grid, 256, 0, stream>>>(Q, Kf, Vf, table, Out);
}

// Round 12
// 89.221 us; speedup vs baseline: 2.3957x; 2.3957x over previous
//
#include <hip/hip_runtime.h>
#include <hip/hip_bf16.h>
#include <math.h>

typedef __attribute__((ext_vector_type(8)))  short short8;
typedef __attribute__((ext_vector_type(4)))  float floatx4;
typedef __attribute__((ext_vector_type(16))) float f32x16;

#define L_SEQ 2048
#define NHEADS 8
#define EDIM 64
#define PLANE (L_SEQ * EDIM) // shorts per (b,h) plane in workspace (131072)
#define LOG2E 1.4426950408889634f

union U8 { unsigned u[4]; short8 s; };

__device__ __forceinline__ unsigned cvt_pk(float lo, float hi) {
    unsigned r;
    asm("v_cvt_pk_bf16_f32 %0, %1, %2" : "=v"(r) : "v"(lo), "v"(hi));
    return r;
}
__device__ __forceinline__ short8 pack8(floatx4 a, floatx4 b) {
    U8 r;
    r.u[0] = cvt_pk(a[0], a[1]); r.u[1] = cvt_pk(a[2], a[3]);
    r.u[2] = cvt_pk(b[0], b[1]); r.u[3] = cvt_pk(b[2], b[3]);
    return r.s;
}
__device__ __forceinline__ unsigned xswap32(unsigned v) {
    return (unsigned)__shfl_xor((int)v, 32);
}

// ---------- prep: K,V fp32 -> bf16 in MFMA-fragment-linear order ----------
__global__ __launch_bounds__(256) void prep_frag(
    const float* __restrict__ K, const float* __restrict__ V,
    unsigned short* __restrict__ Kf, unsigned short* __restrict__ Vf)
{
    __shared__ unsigned short Tk[64][72];   // [row][e]
    __shared__ unsigned short Tv[64][72];   // [e][k]
    const int st  = blockIdx.x;        // 64-seq-row tile (32 tiles)
    const int bh  = blockIdx.y;        // b*8+h
    const int b   = bh >> 3, h = bh & 7;
    const int tid = threadIdx.x;
    const int sb  = st * 64;

    {   // load K rows coalesced -> Tk
        int s0 = tid >> 3, e0 = (tid & 7) * 8;
        #pragma unroll
        for (int j = 0; j < 2; ++j) {
            int s = s0 + j * 32;
            const float* kp = K + ((size_t)(b * L_SEQ + sb + s) * NHEADS + h) * EDIM + e0;
            floatx4 f0 = *(const floatx4*)kp;
            floatx4 f1 = *(const floatx4*)(kp + 4);
            *(short8*)&Tk[s][e0] = pack8(f0, f1);
        }
    }
    {   // load V rows coalesced (lane = e) -> Tv transposed
        int e = tid & 63, sg = tid >> 6;
        #pragma unroll
        for (int j = 0; j < 16; ++j) {
            int s = sg * 16 + j;
            float v = V[((size_t)(b * L_SEQ + sb + s) * NHEADS + h) * EDIM + e];
            union { float f; unsigned u; } cv; cv.f = v;
            Tv[e][s] = (unsigned short)((cv.u + 0x7FFFu + ((cv.u >> 16) & 1u)) >> 16);
        }
    }
    __syncthreads();
    {   // write Kf fragment-linear (coalesced)
        int s2 = tid >> 7, t7 = tid & 127, ec = t7 >> 5, l31 = t7 & 31;
        #pragma unroll
        for (int hi = 0; hi < 2; ++hi) {
            int row = s2 * 32 + l31, e = ec * 16 + hi * 8;
            short8 v = *(const short8*)&Tk[row][e];
            size_t unit = (((size_t)bh * 64 + st * 2 + s2) * 4 + ec) * 64 + hi * 32 + l31;
            *(short8*)&Kf[unit * 8] = v;
        }
    }
    {   // write Vf fragment-linear (coalesced)
        int s2 = tid >> 7, t7 = tid & 127, et = t7 >> 6, lane = t7 & 63;
        #pragma unroll
        for (int c = 0; c < 2; ++c) {
            int e = et * 32 + (lane & 31), k0 = s2 * 32 + c * 16 + (lane >> 5) * 8;
            short8 v = *(const short8*)&Tv[e][k0];
            size_t unit = ((((size_t)bh * 64 + st * 2 + s2) * 2 + et) * 2 + c) * 64 + lane;
            *(short8*)&Vf[unit * 8] = v;
        }
    }
}

// ---------- attention: 64 q-rows/wave (2 groups), 4 kv-quarter waves, no in-loop barriers ----------
__global__ __launch_bounds__(256, 2) void attn_fwd(
    const float* __restrict__ Q, const unsigned short* __restrict__ Kf,
    const unsigned short* __restrict__ Vf, const float* __restrict__ table,
    float* __restrict__ Out)
{
    __shared__ __align__(16) float bias_lds[L_SEQ];   // 8 KB (log2e-scaled)
    __shared__ __align__(16) float osc[2][32][64];    // 16 KB merge scratch, lane-major
    __shared__ float lsc[2][64];

    const int qg   = 31 - blockIdx.x;          // heavy q-groups dispatch first
    const int bh   = blockIdx.y;
    const int b    = bh >> 3, h = bh & 7;
    const int tid  = threadIdx.x;
    const int w    = tid >> 6, lane = tid & 63;
    const int q32  = lane & 31;
    const int hi   = lane >> 5;
    const int hi4  = 4 * hi, hi8 = 8 * hi;
    const int qsA  = qg * 64;                  // group A rows [qsA, qsA+32)
    const int qsB  = qsA + 32;                 // group B rows [qsB, qsB+32)
    const int qrowA = qsA + q32, qrowB = qsB + q32;
    const int nsub = 2 * qg + 2;               // 32-row kv subtiles

    const int dmax = nsub * 32;
    for (int d = tid; d < dmax; d += 256) {
        int bucket;
        if (d < 16) bucket = d;
        else {
            float t = logf((float)d * 0.0625f) / 2.0794415416798357f * 16.0f;
            int bb = 16 + (int)t;
            bucket = bb < 31 ? bb : 31;
        }
        bias_lds[d] = table[bucket * NHEADS + h] * LOG2E;
    }

    // Q B-fragments for both groups
    const float* qpA = Q + ((size_t)(b * L_SEQ + qrowA) * NHEADS + h) * EDIM;
    const float* qpB = Q + ((size_t)(b * L_SEQ + qrowB) * NHEADS + h) * EDIM;
    short8 qfragA[4], qfragB[4];
    #pragma unroll
    for (int ec = 0; ec < 4; ++ec) {
        floatx4 a0 = *(const floatx4*)(qpA + ec * 16 + hi8);
        floatx4 a1 = *(const floatx4*)(qpA + ec * 16 + hi8 + 4);
        qfragA[ec] = pack8(a0, a1);
        floatx4 b0 = *(const floatx4*)(qpB + ec * 16 + hi8);
        floatx4 b1 = *(const floatx4*)(qpB + ec * 16 + hi8 + 4);
        qfragB[ec] = pack8(b0, b1);
    }
    __syncthreads();    // bias ready

    const int len = (nsub + 3) >> 2;
    const int r0  = w * len;
    const int r1  = (r0 + len < nsub) ? r0 + len : nsub;

    const unsigned short* kfb = Kf + (size_t)bh * PLANE + lane * 8;
    const unsigned short* vfb = Vf + (size_t)bh * PLANE + lane * 8;

    // No max-tracking: logits globally bounded -> unnormalized exp2 safe in fp32;
    // partial (O,l) over disjoint kv sets are purely additive.
    float  lA = 0.f, lB = 0.f;
    f32x16 oA[2] = {}, oB[2] = {};

    const float qscale = 0.125f * LOG2E;

    short8 vf0, vf1, vf2, vf3;   // shared V fragments, captured by the lambda

    // softmax + PV for one group, entirely in-register
    auto sm_pv = [&](const f32x16& st, int qrowX, int kv0s, bool diag,
                     float& l_run, f32x16* o_acc) {
        float p[16];
        if (!diag) {
            const float* bptr = &bias_lds[qrowX - kv0s - hi4];
            #pragma unroll
            for (int r = 0; r < 16; ++r)
                p[r] = exp2f(fmaf(qscale, st[r], bptr[-(r & 3) - 8 * (r >> 2)]));
        } else {
            #pragma unroll
            for (int r = 0; r < 16; ++r) {
                int kidx = (r & 3) + 8 * (r >> 2) + hi4;
                int d = q32 - kidx;
                int dc = d < 0 ? 0 : d;
                float ex = exp2f(fmaf(qscale, st[r], bias_lds[dc]));
                p[r] = (d >= 0) ? ex : 0.0f;
            }
        }
        float s8[8], s4[4], s2[2];
        #pragma unroll
        for (int i = 0; i < 8; ++i) s8[i] = p[2*i] + p[2*i+1];
        #pragma unroll
        for (int i = 0; i < 4; ++i) s4[i] = s8[2*i] + s8[2*i+1];
        s2[0] = s4[0] + s4[1]; s2[1] = s4[2] + s4[3];
        float tsum = s2[0] + s2[1];
        l_run += tsum + __shfl_xor(tsum, 32);

        unsigned a0 = cvt_pk(p[0],  p[1]),  b0 = cvt_pk(p[2],  p[3]);
        unsigned c0 = cvt_pk(p[4],  p[5]),  d0 = cvt_pk(p[6],  p[7]);
        unsigned a1 = cvt_pk(p[8],  p[9]),  b1 = cvt_pk(p[10], p[11]);
        unsigned c1 = cvt_pk(p[12], p[13]), d1 = cvt_pk(p[14], p[15]);
        unsigned as0 = xswap32(a0), bs0 = xswap32(b0);
        unsigned cs0 = xswap32(c0), ds0 = xswap32(d0);
        unsigned as1 = xswap32(a1), bs1 = xswap32(b1);
        unsigned cs1 = xswap32(c1), ds1 = xswap32(d1);
        U8 pf0;   // A[q32][k = hi8 + j]
        pf0.u[0] = hi ? cs0 : a0;
        pf0.u[1] = hi ? ds0 : b0;
        pf0.u[2] = hi ? c0  : as0;
        pf0.u[3] = hi ? d0  : bs0;
        U8 pf1;   // A[q32][k = 16 + hi8 + j]
        pf1.u[0] = hi ? cs1 : a1;
        pf1.u[1] = hi ? ds1 : b1;
        pf1.u[2] = hi ? c1  : as1;
        pf1.u[3] = hi ? d1  : bs1;

        __builtin_amdgcn_s_setprio(1);
        o_acc[0] = __builtin_amdgcn_mfma_f32_32x32x16_bf16(pf0.s, vf0, o_acc[0], 0, 0, 0);
        o_acc[0] = __builtin_amdgcn_mfma_f32_32x32x16_bf16(pf1.s, vf1, o_acc[0], 0, 0, 0);
        o_acc[1] = __builtin_amdgcn_mfma_f32_32x32x16_bf16(pf0.s, vf2, o_acc[1], 0, 0, 0);
        o_acc[1] = __builtin_amdgcn_mfma_f32_32x32x16_bf16(pf1.s, vf3, o_acc[1], 0, 0, 0);
        __builtin_amdgcn_s_setprio(0);
    };

    for (int s32 = r0; s32 < r1; ++s32) {
        const int kv0s = s32 * 32;
        const bool doA = (kv0s <= qsA);        // A fully masked past its diagonal

        // one shared load batch feeds both q-groups (2x arithmetic intensity)
        const unsigned short* kp = kfb + (size_t)s32 * 2048;
        const unsigned short* vp = vfb + (size_t)s32 * 2048;
        short8 kf0 = *(const short8*)(kp);
        short8 kf1 = *(const short8*)(kp + 512);
        short8 kf2 = *(const short8*)(kp + 1024);
        short8 kf3 = *(const short8*)(kp + 1536);
        vf0 = *(const short8*)(vp);
        vf1 = *(const short8*)(vp + 512);
        vf2 = *(const short8*)(vp + 1024);
        vf3 = *(const short8*)(vp + 1536);

        f32x16 stA = {}, stB = {};
        __builtin_amdgcn_s_setprio(1);
        if (doA) {
            stA = __builtin_amdgcn_mfma_f32_32x32x16_bf16(kf0, qfragA[0], stA, 0, 0, 0);
            stA = __builtin_amdgcn_mfma_f32_32x32x16_bf16(kf1, qfragA[1], stA, 0, 0, 0);
            stA = __builtin_amdgcn_mfma_f32_32x32x16_bf16(kf2, qfragA[2], stA, 0, 0, 0);
            stA = __builtin_amdgcn_mfma_f32_32x32x16_bf16(kf3, qfragA[3], stA, 0, 0, 0);
        }
        stB = __builtin_amdgcn_mfma_f32_32x32x16_bf16(kf0, qfragB[0], stB, 0, 0, 0);
        stB = __builtin_amdgcn_mfma_f32_32x32x16_bf16(kf1, qfragB[1], stB, 0, 0, 0);
        stB = __builtin_amdgcn_mfma_f32_32x32x16_bf16(kf2, qfragB[2], stB, 0, 0, 0);
        stB = __builtin_amdgcn_mfma_f32_32x32x16_bf16(kf3, qfragB[3], stB, 0, 0, 0);
        __builtin_amdgcn_s_setprio(0);

        if (doA) sm_pv(stA, qrowA, kv0s, kv0s == qsA, lA, oA);
        sm_pv(stB, qrowB, kv0s, kv0s == qsB, lB, oB);
    }

    // ---- additive merge (2-round LDS tree), group A then group B ----
    auto merge_group = [&](float& l_run, f32x16* o_acc) {
        __syncthreads();
        if (w & 1) {
            int slot = w >> 1;
            #pragma unroll
            for (int et = 0; et < 2; ++et)
                #pragma unroll
                for (int r = 0; r < 16; ++r)
                    osc[slot][et * 16 + r][lane] = o_acc[et][r];
            lsc[slot][lane] = l_run;
        }
        __syncthreads();
        if (!(w & 1)) {
            int slot = w >> 1;
            l_run += lsc[slot][lane];
            #pragma unroll
            for (int et = 0; et < 2; ++et)
                #pragma unroll
                for (int r = 0; r < 16; ++r)
                    o_acc[et][r] += osc[slot][et * 16 + r][lane];
        }
        __syncthreads();
        if (w == 2) {
            #pragma unroll
            for (int et = 0; et < 2; ++et)
                #pragma unroll
                for (int r = 0; r < 16; ++r)
                    osc[0][et * 16 + r][lane] = o_acc[et][r];
            lsc[0][lane] = l_run;
        }
        __syncthreads();
        if (w == 0) {
            l_run += lsc[0][lane];
            #pragma unroll
            for (int et = 0; et < 2; ++et)
                #pragma unroll
                for (int r = 0; r < 16; ++r)
                    o_acc[et][r] += osc[0][et * 16 + r][lane];
        }
        __syncthreads();   // w0's reads done before buffer reuse
    };

    merge_group(lA, oA);
    merge_group(lB, oB);

    if (w == 0) {
        float invA = 1.0f / lA, invB = 1.0f / lB;
        #pragma unroll
        for (int r = 0; r < 16; ++r) {
            int qv = (r & 3) + 8 * (r >> 2) + hi4;
            float ivA = __shfl(invA, qv);
            float ivB = __shfl(invB, qv);
            float* opA = Out + ((size_t)(b * L_SEQ + qsA + qv) * NHEADS + h) * EDIM + q32;
            float* opB = Out + ((size_t)(b * L_SEQ + qsB + qv) * NHEADS + h) * EDIM + q32;
            opA[0]  = oA[0][r] * ivA;
            opA[32] = oA[1][r] * ivA;
            opB[0]  = oB[0][r] * ivB;
            opB[32] = oB[1][r] * ivB;
        }
    }
}

extern "C" void kernel_launch(void* const* d_in, const int* in_sizes, int n_in,
                              void* d_out, int out_size, void* d_ws, size_t ws_size,
                              hipStream_t stream) {
    const float* Q     = (const float*)d_in[0];
    const float* K     = (const float*)d_in[1];
    const float* V     = (const float*)d_in[2];
    const float* table = (const float*)d_in[3];
    float* Out = (float*)d_out;
    unsigned short* Kf = (unsigned short*)d_ws;                 // 8.4 MB
    unsigned short* Vf = Kf + (size_t)4 * NHEADS * PLANE;       // 8.4 MB
    (void)in_sizes; (void)n_in; (void)out_size; (void)ws_size;

    dim3 pgrid(32, 32);
    prep_frag<<<pgrid, 256, 0, stream>>>(K, V, Kf, Vf);
    dim3 grid(32, 32);   // 32 q-groups (64 rows, 4 kv-quarters) x (B*H = 32)
    attn_fwd<<<grid, 256, 0, stream>>>(Q, Kf, Vf, table, Out);
}

// Round 13
// 58.467 us; speedup vs baseline: 3.6559x; 1.5260x over previous
//
#include <hip/hip_runtime.h>
#include <hip/hip_bf16.h>
#include <math.h>

typedef __attribute__((ext_vector_type(8)))  short short8;
typedef __attribute__((ext_vector_type(4)))  float floatx4;
typedef __attribute__((ext_vector_type(16))) float f32x16;

#define L_SEQ 2048
#define NHEADS 8
#define EDIM 64
#define PLANE (L_SEQ * EDIM) // shorts per (b,h) plane in workspace (131072)
#define LOG2E 1.4426950408889634f

union U8 { unsigned u[4]; short8 s; };

__device__ __forceinline__ unsigned cvt_pk(float lo, float hi) {
    unsigned r;
    asm("v_cvt_pk_bf16_f32 %0, %1, %2" : "=v"(r) : "v"(lo), "v"(hi));
    return r;
}
__device__ __forceinline__ short8 pack8(floatx4 a, floatx4 b) {
    U8 r;
    r.u[0] = cvt_pk(a[0], a[1]); r.u[1] = cvt_pk(a[2], a[3]);
    r.u[2] = cvt_pk(b[0], b[1]); r.u[3] = cvt_pk(b[2], b[3]);
    return r.s;
}
__device__ __forceinline__ unsigned xswap32(unsigned v) {
    return (unsigned)__shfl_xor((int)v, 32);
}

// ---------- prep: K,V fp32 -> bf16 in MFMA-fragment-linear order ----------
__global__ __launch_bounds__(256) void prep_frag(
    const float* __restrict__ K, const float* __restrict__ V,
    unsigned short* __restrict__ Kf, unsigned short* __restrict__ Vf)
{
    __shared__ unsigned short Tk[64][72];   // [row][e]
    __shared__ unsigned short Tv[64][72];   // [e][k]
    const int st  = blockIdx.x;        // 64-seq-row tile (32 tiles)
    const int bh  = blockIdx.y;        // b*8+h
    const int b   = bh >> 3, h = bh & 7;
    const int tid = threadIdx.x;
    const int sb  = st * 64;

    {   // load K rows coalesced -> Tk
        int s0 = tid >> 3, e0 = (tid & 7) * 8;
        #pragma unroll
        for (int j = 0; j < 2; ++j) {
            int s = s0 + j * 32;
            const float* kp = K + ((size_t)(b * L_SEQ + sb + s) * NHEADS + h) * EDIM + e0;
            floatx4 f0 = *(const floatx4*)kp;
            floatx4 f1 = *(const floatx4*)(kp + 4);
            *(short8*)&Tk[s][e0] = pack8(f0, f1);
        }
    }
    {   // load V rows coalesced (lane = e) -> Tv transposed
        int e = tid & 63, sg = tid >> 6;
        #pragma unroll
        for (int j = 0; j < 16; ++j) {
            int s = sg * 16 + j;
            float v = V[((size_t)(b * L_SEQ + sb + s) * NHEADS + h) * EDIM + e];
            union { float f; unsigned u; } cv; cv.f = v;
            Tv[e][s] = (unsigned short)((cv.u + 0x7FFFu + ((cv.u >> 16) & 1u)) >> 16);
        }
    }
    __syncthreads();
    {   // write Kf fragment-linear (coalesced)
        int s2 = tid >> 7, t7 = tid & 127, ec = t7 >> 5, l31 = t7 & 31;
        #pragma unroll
        for (int hi = 0; hi < 2; ++hi) {
            int row = s2 * 32 + l31, e = ec * 16 + hi * 8;
            short8 v = *(const short8*)&Tk[row][e];
            size_t unit = (((size_t)bh * 64 + st * 2 + s2) * 4 + ec) * 64 + hi * 32 + l31;
            *(short8*)&Kf[unit * 8] = v;
        }
    }
    {   // write Vf fragment-linear (coalesced)
        int s2 = tid >> 7, t7 = tid & 127, et = t7 >> 6, lane = t7 & 63;
        #pragma unroll
        for (int c = 0; c < 2; ++c) {
            int e = et * 32 + (lane & 31), k0 = s2 * 32 + c * 16 + (lane >> 5) * 8;
            short8 v = *(const short8*)&Tv[e][k0];
            size_t unit = ((((size_t)bh * 64 + st * 2 + s2) * 2 + et) * 2 + c) * 64 + lane;
            *(short8*)&Vf[unit * 8] = v;
        }
    }
}

// ---------- attention: 32 q-rows/block, 4 kv-quarter waves, XCD-swizzled grid ----------
__global__ __launch_bounds__(256, 3) void attn_fwd(
    const float* __restrict__ Q, const unsigned short* __restrict__ Kf,
    const unsigned short* __restrict__ Vf, const float* __restrict__ table,
    float* __restrict__ Out)
{
    __shared__ __align__(16) float bias_lds[L_SEQ];   // 8 KB (log2e-scaled)
    __shared__ __align__(16) float osc[2][32][64];    // 16 KB merge scratch, lane-major
    __shared__ float lsc[2][64];

    // XCD-aware swizzle: nwg=2048, hardware round-robins linear id across 8 XCDs.
    // wid = (bid%8)*256 + bid/8 gives XCD x the contiguous work range [x*256,(x+1)*256)
    // = bh in [4x, 4x+4): each XCD's K/V working set is 2 MB (fits 4 MB L2).
    const int bid = blockIdx.x;
    const int wid = (bid & 7) * 256 + (bid >> 3);
    const int bh  = wid >> 6;                  // 0..31
    const int qg  = 63 - (wid & 63);           // heavy q-groups first within XCD
    const int b    = bh >> 3, h = bh & 7;
    const int tid  = threadIdx.x;
    const int w    = tid >> 6, lane = tid & 63;
    const int q32  = lane & 31;
    const int hi   = lane >> 5;
    const int hi4  = 4 * hi, hi8 = 8 * hi;
    const int qs   = qg * 32;
    const int qrow = qs + q32;
    const int nsub = qg + 1;                   // 32-row kv subtiles

    const int dmax = nsub * 32;
    for (int d = tid; d < dmax; d += 256) {
        int bucket;
        if (d < 16) bucket = d;
        else {
            float t = logf((float)d * 0.0625f) / 2.0794415416798357f * 16.0f;
            int bb = 16 + (int)t;
            bucket = bb < 31 ? bb : 31;
        }
        bias_lds[d] = table[bucket * NHEADS + h] * LOG2E;
    }

    const float* qptr = Q + ((size_t)(b * L_SEQ + qrow) * NHEADS + h) * EDIM;
    short8 qfrag[4];
    #pragma unroll
    for (int ec = 0; ec < 4; ++ec) {
        floatx4 f0 = *(const floatx4*)(qptr + ec * 16 + hi8);
        floatx4 f1 = *(const floatx4*)(qptr + ec * 16 + hi8 + 4);
        qfrag[ec] = pack8(f0, f1);
    }
    __syncthreads();    // bias ready

    // this wave's contiguous kv-subtile range
    const int len = (nsub + 3) >> 2;
    const int r0  = w * len;
    const int r1  = (r0 + len < nsub) ? r0 + len : nsub;

    const unsigned short* kfb = Kf + (size_t)bh * PLANE + lane * 8;
    const unsigned short* vfb = Vf + (size_t)bh * PLANE + lane * 8;

    // No max-tracking: logits globally bounded -> unnormalized exp2 safe in fp32;
    // partial (O,l) over disjoint kv sets are purely additive.
    float  l_run = 0.f;
    f32x16 o_acc[2] = {};   // [et]: col e = et*32+q32, row q = (r&3)+8*(r>>2)+hi4

    const float qscale = 0.125f * LOG2E;
    for (int s32 = r0; s32 < r1; ++s32) {
        const bool diag = (s32 == qg);
        const int  kv0s = s32 * 32;

        // issue ALL K and V fragment loads up front; counted vmcnt means the
        // first QK MFMA waits only on K, V stays in flight under QK+softmax
        const unsigned short* kp = kfb + (size_t)s32 * 2048;
        const unsigned short* vp = vfb + (size_t)s32 * 2048;
        short8 kf0 = *(const short8*)(kp);
        short8 kf1 = *(const short8*)(kp + 512);
        short8 kf2 = *(const short8*)(kp + 1024);
        short8 kf3 = *(const short8*)(kp + 1536);
        short8 vf0 = *(const short8*)(vp);
        short8 vf1 = *(const short8*)(vp + 512);
        short8 vf2 = *(const short8*)(vp + 1024);
        short8 vf3 = *(const short8*)(vp + 1536);

        // S^T = K · Q^T : lane holds S[q=q32][k_local=(r&3)+8*(r>>2)+hi4]
        f32x16 st = {};
        __builtin_amdgcn_s_setprio(1);
        st = __builtin_amdgcn_mfma_f32_32x32x16_bf16(kf0, qfrag[0], st, 0, 0, 0);
        st = __builtin_amdgcn_mfma_f32_32x32x16_bf16(kf1, qfrag[1], st, 0, 0, 0);
        st = __builtin_amdgcn_mfma_f32_32x32x16_bf16(kf2, qfrag[2], st, 0, 0, 0);
        st = __builtin_amdgcn_mfma_f32_32x32x16_bf16(kf3, qfrag[3], st, 0, 0, 0);
        __builtin_amdgcn_s_setprio(0);

        // p = exp2(qscale*S + bias) unnormalized; causal mask -> 0
        float p[16];
        if (!diag) {
            const float* bptr = &bias_lds[qrow - kv0s - hi4];
            #pragma unroll
            for (int r = 0; r < 16; ++r)
                p[r] = exp2f(fmaf(qscale, st[r], bptr[-(r & 3) - 8 * (r >> 2)]));
        } else {
            #pragma unroll
            for (int r = 0; r < 16; ++r) {
                int kidx = (r & 3) + 8 * (r >> 2) + hi4;
                int d = q32 - kidx;
                int dc = d < 0 ? 0 : d;
                float ex = exp2f(fmaf(qscale, st[r], bias_lds[dc]));
                p[r] = (d >= 0) ? ex : 0.0f;
            }
        }

        // row sum: in-lane tree + one cross-half exchange
        float s8[8], s4[4], s2[2];
        #pragma unroll
        for (int i = 0; i < 8; ++i) s8[i] = p[2*i] + p[2*i+1];
        #pragma unroll
        for (int i = 0; i < 4; ++i) s4[i] = s8[2*i] + s8[2*i+1];
        s2[0] = s4[0] + s4[1]; s2[1] = s4[2] + s4[3];
        float tsum = s2[0] + s2[1];
        l_run += tsum + __shfl_xor(tsum, 32);

        // P -> bf16 A-fragments in-register; cross-half via shfl_xor(32)
        unsigned a0 = cvt_pk(p[0],  p[1]),  b0 = cvt_pk(p[2],  p[3]);
        unsigned c0 = cvt_pk(p[4],  p[5]),  d0 = cvt_pk(p[6],  p[7]);
        unsigned a1 = cvt_pk(p[8],  p[9]),  b1 = cvt_pk(p[10], p[11]);
        unsigned c1 = cvt_pk(p[12], p[13]), d1 = cvt_pk(p[14], p[15]);
        unsigned as0 = xswap32(a0), bs0 = xswap32(b0);
        unsigned cs0 = xswap32(c0), ds0 = xswap32(d0);
        unsigned as1 = xswap32(a1), bs1 = xswap32(b1);
        unsigned cs1 = xswap32(c1), ds1 = xswap32(d1);
        U8 pf0;   // A[q32][k = hi8 + j]
        pf0.u[0] = hi ? cs0 : a0;
        pf0.u[1] = hi ? ds0 : b0;
        pf0.u[2] = hi ? c0  : as0;
        pf0.u[3] = hi ? d0  : bs0;
        U8 pf1;   // A[q32][k = 16 + hi8 + j]
        pf1.u[0] = hi ? cs1 : a1;
        pf1.u[1] = hi ? ds1 : b1;
        pf1.u[2] = hi ? c1  : as1;
        pf1.u[3] = hi ? d1  : bs1;

        // O += P·V  (2 e-tiles x 2 k-chunks), fragment registers already in flight
        __builtin_amdgcn_s_setprio(1);
        o_acc[0] = __builtin_amdgcn_mfma_f32_32x32x16_bf16(pf0.s, vf0, o_acc[0], 0, 0, 0);
        o_acc[0] = __builtin_amdgcn_mfma_f32_32x32x16_bf16(pf1.s, vf1, o_acc[0], 0, 0, 0);
        o_acc[1] = __builtin_amdgcn_mfma_f32_32x32x16_bf16(pf0.s, vf2, o_acc[1], 0, 0, 0);
        o_acc[1] = __builtin_amdgcn_mfma_f32_32x32x16_bf16(pf1.s, vf3, o_acc[1], 0, 0, 0);
        __builtin_amdgcn_s_setprio(0);
    }

    // ---- additive merge of the 4 kv-quarters (2-round LDS tree, lane-major) ----
    __syncthreads();
    if (w & 1) {                         // waves 1,3 -> slots 0,1
        int slot = w >> 1;
        #pragma unroll
        for (int et = 0; et < 2; ++et)
            #pragma unroll
            for (int r = 0; r < 16; ++r)
                osc[slot][et * 16 + r][lane] = o_acc[et][r];
        lsc[slot][lane] = l_run;
    }
    __syncthreads();
    if (!(w & 1)) {                      // waves 0,2 absorb
        int slot = w >> 1;
        l_run += lsc[slot][lane];
        #pragma unroll
        for (int et = 0; et < 2; ++et)
            #pragma unroll
            for (int r = 0; r < 16; ++r)
                o_acc[et][r] += osc[slot][et * 16 + r][lane];
    }
    __syncthreads();
    if (w == 2) {                        // wave 2 -> slot 0
        #pragma unroll
        for (int et = 0; et < 2; ++et)
            #pragma unroll
            for (int r = 0; r < 16; ++r)
                osc[0][et * 16 + r][lane] = o_acc[et][r];
        lsc[0][lane] = l_run;
    }
    __syncthreads();
    if (w == 0) {
        l_run += lsc[0][lane];
        #pragma unroll
        for (int et = 0; et < 2; ++et)
            #pragma unroll
            for (int r = 0; r < 16; ++r)
                o_acc[et][r] += osc[0][et * 16 + r][lane];

        // epilogue: O / l ; l broadcast via shfl from the lane owning that q-row
        float inv = 1.0f / l_run;
        #pragma unroll
        for (int r = 0; r < 16; ++r) {
            int qv = (r & 3) + 8 * (r >> 2) + hi4;
            float iv = __shfl(inv, qv);
            float* op = Out + ((size_t)(b * L_SEQ + qs + qv) * NHEADS + h) * EDIM + q32;
            op[0]  = o_acc[0][r] * iv;
            op[32] = o_acc[1][r] * iv;
        }
    }
}

extern "C" void kernel_launch(void* const* d_in, const int* in_sizes, int n_in,
                              void* d_out, int out_size, void* d_ws, size_t ws_size,
                              hipStream_t stream) {
    const float* Q     = (const float*)d_in[0];
    const float* K     = (const float*)d_in[1];
    const float* V     = (const float*)d_in[2];
    const float* table = (const float*)d_in[3];
    float* Out = (float*)d_out;
    unsigned short* Kf = (unsigned short*)d_ws;                 // 8.4 MB
    unsigned short* Vf = Kf + (size_t)4 * NHEADS * PLANE;       // 8.4 MB
    (void)in_sizes; (void)n_in; (void)out_size; (void)ws_size;

    dim3 pgrid(32, 32);
    prep_frag<<<pgrid, 256, 0, stream>>>(K, V, Kf, Vf);
    attn_fwd<<<dim3(2048), 256, 0, stream>>>(Q, Kf, Vf, table, Out);
}